// Round 1
// baseline (303.072 us; speedup 1.0000x reference)
//
#include <hip/hip_runtime.h>

// Per-pixel predicted 3x3 filtering:
// out[b,c,h,w] = sum_{f=0..1} sum_{ki,kj=0..2} k[b, f*9+ki*3+kj, h, w] *
//                x[b, f*64+c, h+ki-1, w+kj-1]          (zero-padded)
//              + k[b, 18, h, w] * skip[b,c,h,w]
//
// B=4, C=64, NF=2, H=W=256, K_SLOTS=19. All fp32.
// Memory-bound: ~288 MB min traffic -> ~46 us floor at 6.3 TB/s.

constexpr int Hh = 256;
constexpr int Ww = 256;
constexpr int HW = Hh * Ww;
constexpr int C  = 64;
constexpr int NF = 2;
constexpr int KS = 19;

__global__ __launch_bounds__(256) void filt_kernel(
    const float* __restrict__ kk,
    const float* __restrict__ x,
    const float* __restrict__ skip,
    float* __restrict__ out) {
  // block = one (b, h) row; 256 threads = 64 w-groups x 4 channel-quarters
  const int bh  = blockIdx.x;
  const int b   = bh >> 8;        // / 256
  const int h   = bh & 255;
  const int tid = threadIdx.x;
  const int wg  = tid & 63;       // w-group: 4 pixels each
  const int cq  = tid >> 6;       // channel quarter: 16 channels each
  const int w0  = wg << 2;

  // Load the 19 per-pixel kernel coefficients (float4 across 4 pixels).
  // Reused for all 16 channels this thread computes.
  const float* kbase = kk + (size_t)b * KS * HW + (size_t)h * Ww + w0;
  float kv[KS][4];
#pragma unroll
  for (int s = 0; s < KS; ++s) {
    float4 t = *(const float4*)(kbase + (size_t)s * HW);
    kv[s][0] = t.x; kv[s][1] = t.y; kv[s][2] = t.z; kv[s][3] = t.w;
  }

  const float* xb = x    + (size_t)b * NF * C * HW;
  const float* sb = skip + (size_t)b * C * HW + (size_t)h * Ww + w0;
  float*       ob = out  + (size_t)b * C * HW + (size_t)h * Ww + w0;

  const bool wlo = (w0 > 0);          // w0-1 valid?
  const bool whi = (w0 + 4 < Ww);     // w0+4 valid?

  for (int ci = 0; ci < 16; ++ci) {
    const int c = cq * 16 + ci;

    float4 sv = *(const float4*)(sb + (size_t)c * HW);
    float acc[4] = { kv[18][0] * sv.x, kv[18][1] * sv.y,
                     kv[18][2] * sv.z, kv[18][3] * sv.w };

#pragma unroll
    for (int f = 0; f < NF; ++f) {
      const float* xc = xb + (size_t)(f * C + c) * HW;
#pragma unroll
      for (int ki = 0; ki < 3; ++ki) {
        const int hh = h + ki - 1;
        if (hh >= 0 && hh < Hh) {     // block-uniform branch (h uniform)
          const float* xr = xc + (size_t)hh * Ww;
          // 6 consecutive x values covering columns w0-1 .. w0+4
          float v[6];
          v[0] = wlo ? xr[w0 - 1] : 0.0f;
          float4 xm = *(const float4*)(xr + w0);   // 16B-aligned
          v[1] = xm.x; v[2] = xm.y; v[3] = xm.z; v[4] = xm.w;
          v[5] = whi ? xr[w0 + 4] : 0.0f;
#pragma unroll
          for (int kj = 0; kj < 3; ++kj) {
            const int s = f * 9 + ki * 3 + kj;
#pragma unroll
            for (int p = 0; p < 4; ++p)
              acc[p] = fmaf(kv[s][p], v[p + kj], acc[p]);
          }
        }
      }
    }

    float4 o;
    o.x = acc[0]; o.y = acc[1]; o.z = acc[2]; o.w = acc[3];
    *(float4*)(ob + (size_t)c * HW) = o;
  }
}

extern "C" void kernel_launch(void* const* d_in, const int* in_sizes, int n_in,
                              void* d_out, int out_size, void* d_ws, size_t ws_size,
                              hipStream_t stream) {
  const float* kk = (const float*)d_in[0];   // [4, 19, 256, 256]
  const float* x  = (const float*)d_in[1];   // [4, 128, 256, 256]
  const float* sk = (const float*)d_in[2];   // [4, 64, 256, 256]
  float* out = (float*)d_out;                // [4, 64, 256, 256]

  dim3 grid(4 * Hh);   // one block per (b, h) row
  dim3 block(256);
  filt_kernel<<<grid, block, 0, stream>>>(kk, x, sk, out);
}

// Round 3
// 278.870 us; speedup vs baseline: 1.0868x; 1.0868x over previous
//
#include <hip/hip_runtime.h>

// Per-pixel predicted 3x3 filtering, fp32:
// out[b,c,h,w] = sum_{f,ki,kj} k[b, f*9+ki*3+kj, h, w] * x[b, f*64+c, h+ki-1, w+kj-1]
//              + k[b, 18, h, w] * skip[b,c,h,w]
// B=4, C=64, NF=2, H=W=256. Min HBM traffic ~288 MB -> ~46 us floor @ 6.3 TB/s.
//
// R2 structure: grid = (b, h, cg) = 4*256*4 blocks. Block = 256 threads =
// 4 waves; each wave = the full 256-px row (4 px/lane via float4) and owns
// 4 channels. k row staged in LDS (19 KB), shared by all 4 waves.
// Edge pixels via intra-wave shuffle: wave spans the whole row, so
// lane 0 / lane 63 masks implement the zero padding exactly.

constexpr int Hh = 256;
constexpr int Ww = 256;
constexpr int HW = Hh * Ww;
constexpr int C  = 64;
constexpr int NF = 2;
constexpr int KS = 19;

__global__ __launch_bounds__(256) void filt_kernel(
    const float* __restrict__ kk,
    const float* __restrict__ x,
    const float* __restrict__ skip,
    float* __restrict__ out) {
  const int blk  = blockIdx.x;       // ((b*256 + h) << 2) | cg
  const int cg   = blk & 3;
  const int h    = (blk >> 2) & 255;
  const int b    = blk >> 10;
  const int tid  = threadIdx.x;
  const int lane = tid & 63;
  const int wv   = tid >> 6;         // wave id 0..3
  const int w0   = lane << 2;        // 4 pixels per lane

  __shared__ float lds_k[KS][Ww];    // 19456 B

  // Stage the 19 k-rows cooperatively (coalesced 1 KB per slot per wave).
  const float* kb = kk + (size_t)b * KS * HW + (size_t)h * Ww;
  for (int s = wv; s < KS; s += 4)
    *(float4*)&lds_k[s][w0] = *(const float4*)(kb + (size_t)s * HW + w0);
  __syncthreads();

  const int c0 = cg * 16 + wv * 4;   // this wave's 4 channels
  const float* xb = x    + (size_t)b * NF * C * HW;
  const float* sb = skip + ((size_t)b * C + c0) * HW + (size_t)h * Ww + w0;
  float*       ob = out  + ((size_t)b * C + c0) * HW + (size_t)h * Ww + w0;

  // acc init = skip * k[18]
  float4 k18 = *(const float4*)&lds_k[18][w0];
  float acc[4][4];
#pragma unroll
  for (int ch = 0; ch < 4; ++ch) {
    float4 sv = *(const float4*)(sb + (size_t)ch * HW);
    acc[ch][0] = k18.x * sv.x; acc[ch][1] = k18.y * sv.y;
    acc[ch][2] = k18.z * sv.z; acc[ch][3] = k18.w * sv.w;
  }

#pragma unroll
  for (int f = 0; f < NF; ++f) {
    const float* xf = xb + (size_t)(f * C + c0) * HW;
#pragma unroll
    for (int ki = 0; ki < 3; ++ki) {
      const int hh = h + ki - 1;
      if (hh < 0 || hh >= Hh) continue;          // block-uniform
      const float* xr = xf + (size_t)hh * Ww + w0;

      float v[4][6];                             // 6-wide window per channel
#pragma unroll
      for (int ch = 0; ch < 4; ++ch) {
        float4 xm = *(const float4*)(xr + (size_t)ch * HW);
        v[ch][1] = xm.x; v[ch][2] = xm.y; v[ch][3] = xm.z; v[ch][4] = xm.w;
      }
#pragma unroll
      for (int ch = 0; ch < 4; ++ch) {
        float lf = __shfl_up(v[ch][4], 1);       // neighbor's w0-1
        float rg = __shfl_down(v[ch][1], 1);     // neighbor's w0+4
        v[ch][0] = (lane == 0)  ? 0.0f : lf;     // w == -1  -> pad
        v[ch][5] = (lane == 63) ? 0.0f : rg;     // w == 256 -> pad
      }
#pragma unroll
      for (int kj = 0; kj < 3; ++kj) {
        const int s = f * 9 + ki * 3 + kj;
        float4 kw = *(const float4*)&lds_k[s][w0];
#pragma unroll
        for (int ch = 0; ch < 4; ++ch) {
          acc[ch][0] = fmaf(kw.x, v[ch][0 + kj], acc[ch][0]);
          acc[ch][1] = fmaf(kw.y, v[ch][1 + kj], acc[ch][1]);
          acc[ch][2] = fmaf(kw.z, v[ch][2 + kj], acc[ch][2]);
          acc[ch][3] = fmaf(kw.w, v[ch][3 + kj], acc[ch][3]);
        }
      }
    }
  }

#pragma unroll
  for (int ch = 0; ch < 4; ++ch) {
    float4 o = make_float4(acc[ch][0], acc[ch][1], acc[ch][2], acc[ch][3]);
    *(float4*)(ob + (size_t)ch * HW) = o;
  }
}

extern "C" void kernel_launch(void* const* d_in, const int* in_sizes, int n_in,
                              void* d_out, int out_size, void* d_ws, size_t ws_size,
                              hipStream_t stream) {
  const float* kk = (const float*)d_in[0];   // [4, 19, 256, 256]
  const float* x  = (const float*)d_in[1];   // [4, 128, 256, 256]
  const float* sk = (const float*)d_in[2];   // [4, 64, 256, 256]
  float* out = (float*)d_out;                // [4, 64, 256, 256]

  dim3 grid(4 * Hh * 4);   // (b, h) rows x 4 channel groups
  dim3 block(256);
  filt_kernel<<<grid, block, 0, stream>>>(kk, x, sk, out);
}